// Round 6
// baseline (109.126 us; speedup 1.0000x reference)
//
#include <hip/hip_runtime.h>

#define NB   128
#define NN   32
#define OBS  64
#define ACTD 16
#define HID  64

typedef __attribute__((ext_vector_type(8))) short bf16x8;
typedef __attribute__((ext_vector_type(4))) float f32x4;

__device__ __forceinline__ float leaky(float v) { return v >= 0.f ? v : 0.01f * v; }
__device__ __forceinline__ float wsum64(float p) {
#pragma unroll
    for (int off = 32; off; off >>= 1) p += __shfl_xor(p, off);
    return p;
}
__device__ __forceinline__ unsigned short f2bf(float f) {
    union { float f; unsigned u; } v; v.f = f;
    unsigned r = (v.u + 0x7FFFu + ((v.u >> 16) & 1)) >> 16;
    return (unsigned short)r;
}
// swizzled short-offset for a [*][64] bf16 tile: row*64 + ((col>>3 ^ row&7)<<3 | col&7)
__device__ __forceinline__ int swz(int row, int col) {
    return row * 64 + ((((col >> 3) ^ (row & 7)) << 3) | (col & 7));
}

// one row per wave: O[h] = (ACT?leaky:id)(bias[h] + sum_k X[k]*W[k*64+h])
template<int K, bool ACT>
__device__ __forceinline__ void layer1(const float* Xrow, const float* __restrict__ W,
                                       const float* __restrict__ bias,
                                       float* Orow, float* __restrict__ Og, int h)
{
    float a0 = bias ? bias[h] : 0.f;
#pragma unroll 4
    for (int k = 0; k < K; ++k)
        a0 = fmaf(Xrow[k], W[k * 64 + h], a0);
    if (ACT) a0 = leaky(a0);
    if (Orow) Orow[h] = a0;
    if (Og)   Og[h]   = a0;
}

// ---------------- kernel 0: M = av2_w @ fv1b (f32 + swizzled bf16 M^T), c = av2_b @ fv1b ----------------
__global__ __launch_bounds__(256)
void mm64_kernel(const float* __restrict__ av2_w, const float* __restrict__ av2_b,
                 const float* __restrict__ fv1_w,   // 128x64; rows 64..127 = fv1b
                 float* __restrict__ M, unsigned short* __restrict__ MT,
                 float* __restrict__ c)
{
    const int t = threadIdx.x, h = t & 63, jg = t >> 6;
    __shared__ float sA[64 * 64];
    for (int i = t; i < 4096; i += 256) sA[i] = av2_w[i];
    __syncthreads();
    const float* W = fv1_w + 64 * 64;
    float acc[16];
#pragma unroll
    for (int i = 0; i < 16; ++i) acc[i] = 0.f;
    for (int m = 0; m < 64; ++m) {
        const float w = W[m * 64 + h];
#pragma unroll
        for (int i = 0; i < 16; ++i)
            acc[i] = fmaf(sA[(jg + 4 * i) * 64 + m], w, acc[i]);
    }
#pragma unroll
    for (int i = 0; i < 16; ++i) {
        const int k = jg + 4 * i;
        M[k * 64 + h] = acc[i];
        MT[swz(h, k)] = f2bf(acc[i]);   // MT[h][k] = M[k][h], bf16, swizzled
    }
    if (t < 64) {
        float s = 0.f;
        for (int m = 0; m < 64; ++m) s = fmaf(av2_b[m], W[m * 64 + t], s);
        c[t] = s;
    }
}

// ---------------- kernel 1: row-parallel setup (4 rows/block, 1 row/wave) ----------------
__global__ __launch_bounds__(256)
void setup_kernel(const float* __restrict__ states,    // R,64  (R = B*N = 4096)
                  const float* __restrict__ policies,  // R,16
                  const float* __restrict__ actions,   // R,16
                  const float* __restrict__ kw1_w, const float* __restrict__ kw1_b,
                  const float* __restrict__ kw2_w, const float* __restrict__ kw2_b,
                  const float* __restrict__ qw1_w, const float* __restrict__ qw1_b,
                  const float* __restrict__ qw2_w, const float* __restrict__ qw2_b,
                  const float* __restrict__ ko1_w, const float* __restrict__ ko1_b,
                  const float* __restrict__ ko2_w, const float* __restrict__ ko2_b,
                  const float* __restrict__ qo1_w, const float* __restrict__ qo1_b,
                  const float* __restrict__ qo2_w, const float* __restrict__ qo2_b,
                  const float* __restrict__ av1_w, const float* __restrict__ av1_b,
                  const float* __restrict__ fv1_w, const float* __restrict__ fv1_b,
                  const float* __restrict__ M, const float* __restrict__ c,
                  float* __restrict__ kz,    float* __restrict__ qz,
                  float* __restrict__ kq,    float* __restrict__ kb,
                  float* __restrict__ baseq, float* __restrict__ deltaq,
                  float* __restrict__ basev, float* __restrict__ deltav,
                  float* __restrict__ pre,   float* __restrict__ vpf)
{
    const int r0 = blockIdx.x * 4;        // 1024 blocks × 4 rows
    const int t = threadIdx.x, h = t & 63, jg = t >> 6;
    const int r = r0 + jg;                // this wave's row

    __shared__ float sST[4 * 64];
    __shared__ float sACT[4 * 16], sPOL[4 * 16], sDAP[4 * 16];
    __shared__ float sH[4 * 64], sKZ[4 * 64], sQZ[4 * 64], sKOBS[4 * 64], sBV[4 * 64];
    __shared__ float sSRC[4 * 80];
    __shared__ float T[4096];             // qo2_w row-major, xor-swizzled cols

    if (t < 256) sST[t] = states[r0 * 64 + t];
    if (t < 64) {
        const float av = actions [r0 * 16 + t];
        const float pv = policies[r0 * 16 + t];
        sACT[t] = av; sPOL[t] = pv; sDAP[t] = av - pv;
    }
    for (int i = t; i < 4096; i += 256) {
        const int hh = i >> 6, d = i & 63;
        T[hh * 64 + (d ^ (hh & 31))] = qo2_w[i];
    }
    __syncthreads();   // the only block-wide barrier

    float* ST = sST + jg * 64;
    float* Hr = sH + jg * 64;

    // kz, qz
    layer1<64, true >(ST, kw1_w, kw1_b, Hr, nullptr, h);
    layer1<64, false>(Hr, kw2_w, kw2_b, sKZ + jg * 64, kz + r * 64, h);
    layer1<64, true >(ST, qw1_w, qw1_b, Hr, nullptr, h);
    layer1<64, false>(Hr, qw2_w, qw2_b, sQZ + jg * 64, qz + r * 64, h);

    // wzd = sigmoid(kz.qz/8)
    const float wzd = 1.f / (1.f + __expf(-wsum64(sKZ[jg * 64 + h] * sQZ[jg * 64 + h]) * 0.125f));

    // source row [st, wzd*act + (1-wzd)*pol]
    sSRC[jg * 80 + h] = ST[h];
    if (h < 16)
        sSRC[jg * 80 + 64 + h] = wzd * sACT[jg * 16 + h] + (1.f - wzd) * sPOL[jg * 16 + h];

    // kobs
    layer1<80, true >(sSRC + jg * 80, ko1_w, ko1_b, Hr, nullptr, h);
    layer1<64, false>(Hr, ko2_w, ko2_b, sKOBS + jg * 64, nullptr, h);

    // kq[h] = 0.125*sum_d qo2_w[h][d]*kobs[d]; kb = 0.125*qo2_b.kobs
    {
        float k0 = 0.f;
#pragma unroll 4
        for (int d = 0; d < 64; ++d)
            k0 = fmaf(sKOBS[jg * 64 + d], T[h * 64 + (d ^ (h & 31))], k0);
        kq[r * 64 + h] = k0 * 0.125f;
        const float s0 = wsum64(qo2_b[h] * sKOBS[jg * 64 + h]);
        if (h == 0) kb[r] = s0 * 0.125f;
    }

    // SP row [st, pol]
    if (h < 16) sSRC[jg * 80 + 64 + h] = sPOL[jg * 16 + h];

    layer1<80, false>(sSRC + jg * 80, qo1_w,        qo1_b,   nullptr, baseq  + r * 64, h);
    layer1<16, false>(sDAP + jg * 16, qo1_w + 4096, nullptr, nullptr, deltaq + r * 64, h);
    layer1<80, false>(sSRC + jg * 80, av1_w,        av1_b,   sBV + jg * 64, basev + r * 64, h);
    layer1<16, false>(sDAP + jg * 16, av1_w + 4096, nullptr, nullptr, deltav + r * 64, h);

    // vpf = leaky(basev)@M + c ; pre = st@fv1a + fb1
    Hr[h] = leaky(sBV[jg * 64 + h]);
    layer1<64, false>(Hr, M,     c,     nullptr, vpf + r * 64, h);
    layer1<64, false>(ST, fv1_w, fv1_b, nullptr, pre + r * 64, h);
}

// ---------------- kernel 2: per-(b,a) main ----------------
__global__ __launch_bounds__(256)
void main_kernel(const float* __restrict__ kz,    const float* __restrict__ qz,
                 const float* __restrict__ kq,    const float* __restrict__ kb,
                 const float* __restrict__ baseq, const float* __restrict__ deltaq,
                 const float* __restrict__ basev, const float* __restrict__ deltav,
                 const float* __restrict__ pre,   const float* __restrict__ vpf,
                 const unsigned short* __restrict__ MT,  // bf16 swizzled M^T [64][64]
                 const float* __restrict__ c,
                 const float* __restrict__ fv2_w, const float* __restrict__ fv2_b,
                 float* __restrict__ out_value,   // B,N,N
                 float* __restrict__ out_wz,      // B,N,N
                 float* __restrict__ out_wobs)    // B,N,N
{
    const int bid0 = blockIdx.x;
    const int bid  = (bid0 & 7) * 512 + (bid0 >> 3);   // XCD swizzle (4096 = 8*512)
    const int b = bid >> 5, a = bid & 31;
    const int t = threadIdx.x, lane = t & 63, jg = t >> 6;

    __shared__ float poolQZ[2048];                       // qz[b]
    __shared__ __align__(16) unsigned short sMT[4096];   // M^T bf16 swizzled
    __shared__ __align__(16) unsigned short sHV[2048];   // HV bf16 swizzled [32][64]
    __shared__ float sC[2048];                           // C = HV@M  [32][64]
    __shared__ float s_sc[NN], s_w[NN], s_wzr[NN], s_hbarM[HID];

    for (int i = t; i < 2048; i += 256) {
        poolQZ[i] = qz[b * 2048 + i];
        ((unsigned int*)sMT)[i] = ((const unsigned int*)MT)[i];
    }
    const float kzv = kz[(b * 32 + a) * 64 + lane];
    const float kqv = kq[(b * 32 + a) * 64 + lane];
    const float kbv = kb[b * 32 + a];
    __syncthreads();

    // weight_z row (8 j per wave) + write out_wz
#pragma unroll
    for (int i = 0; i < 8; ++i) {
        const int j = jg * 8 + i;
        const float p = wsum64(kzv * poolQZ[j * 64 + lane]);
        const float w = 1.f / (1.f + __expf(-p * 0.125f));
        if (lane == 0) { s_wzr[j] = w; out_wz[b * 1024 + a * 32 + j] = w; }
    }
    // scores
#pragma unroll
    for (int i = 0; i < 8; ++i) {
        const int j = jg * 8 + i;
        const int rb = (b * 32 + j) * 64 + lane;
        const float hq = leaky(baseq[rb] + s_wzr[j] * deltaq[rb]);
        const float p = wsum64(hq * kqv);
        if (lane == 0) s_sc[j] = p + kbv;
    }
    __syncthreads();

    // softmax (t<32) ; HV build -> bf16 swizzled
    if (t < 32) {
        float m = -1e30f;
        for (int j = 0; j < 32; ++j) m = fmaxf(m, s_sc[j]);
        float s = 0.f;
        for (int j = 0; j < 32; ++j) s += __expf(s_sc[j] - m);
        const float w = __expf(s_sc[t] - m) / s;
        s_w[t] = w;
        out_wobs[b * 1024 + a * 32 + t] = w;
    }
    for (int i = t; i < 2048; i += 256) {
        const int row = i >> 6, col = i & 63;
        const float hv = leaky(basev[b * 2048 + i] + s_wzr[row] * deltav[b * 2048 + i]);
        sHV[swz(row, col)] = f2bf(hv);
    }
    __syncthreads();

    // C = HV(32x64) @ M(64x64) via MFMA; wave jg owns output cols jg*16..+15
    {
        const int lm  = lane & 15;     // A row-in-tile / B,C col-in-tile
        const int kb8 = lane >> 4;     // k-group
        const int bcol = jg * 16 + lm;
        f32x4 acc0 = {0.f, 0.f, 0.f, 0.f}, acc1 = {0.f, 0.f, 0.f, 0.f};
#pragma unroll
        for (int k0 = 0; k0 < 64; k0 += 32) {
            const int g = (k0 >> 3) + kb8;          // k/8 group index
            const bf16x8 bf = *(const bf16x8*)&sMT[bcol * 64 + (((g ^ (bcol & 7)) << 3))];
            const bf16x8 a0 = *(const bf16x8*)&sHV[lm * 64 + (((g ^ (lm & 7)) << 3))];
            const bf16x8 a1 = *(const bf16x8*)&sHV[(16 + lm) * 64 + (((g ^ (lm & 7)) << 3))];
            acc0 = __builtin_amdgcn_mfma_f32_16x16x32_bf16(a0, bf, acc0, 0, 0, 0);
            acc1 = __builtin_amdgcn_mfma_f32_16x16x32_bf16(a1, bf, acc1, 0, 0, 0);
        }
#pragma unroll
        for (int rr = 0; rr < 4; ++rr) {
            sC[(kb8 * 4 + rr) * 64 + bcol]        = acc0[rr];
            sC[(16 + kb8 * 4 + rr) * 64 + bcol]   = acc1[rr];
        }
    }
    __syncthreads();

    // hbarM[h] = sum_j w[j] * C[j][h]
    if (t < 64) {
        float acc = 0.f;
        for (int j = 0; j < 32; ++j) acc = fmaf(s_w[j], sC[j * 64 + t], acc);
        s_hbarM[t] = acc;
    }
    __syncthreads();

    // G = pre + (hbarM - w_j*C_j + (1-w)c + w*vpf)/32 ; value = leaky(G).fv2 + fb2
    {
        const float ch  = c[lane];
        const float fvh = fv2_w[lane];
        const float fb2 = fv2_b[0];
        const float hb  = s_hbarM[lane];
#pragma unroll
        for (int i = 0; i < 8; ++i) {
            const int j = jg + 4 * i;
            const float wj = s_w[j];
            const int rb = (b * 32 + j) * 64 + lane;
            float g = pre[rb] + (hb - wj * sC[j * 64 + lane] + (1.f - wj) * ch + wj * vpf[rb]) * (1.f / 32.f);
            g = leaky(g);
            const float p = wsum64(g * fvh);
            if (lane == 0) out_value[b * 1024 + a * 32 + j] = p + fb2;
        }
    }
}

extern "C" void kernel_launch(void* const* d_in, const int* in_sizes, int n_in,
                              void* d_out, int out_size, void* d_ws, size_t ws_size,
                              hipStream_t stream)
{
    const float* states   = (const float*)d_in[0];
    const float* policies = (const float*)d_in[1];
    const float* actions  = (const float*)d_in[2];
    const float* kw1_w = (const float*)d_in[3];  const float* kw1_b = (const float*)d_in[4];
    const float* kw2_w = (const float*)d_in[5];  const float* kw2_b = (const float*)d_in[6];
    const float* qw1_w = (const float*)d_in[7];  const float* qw1_b = (const float*)d_in[8];
    const float* qw2_w = (const float*)d_in[9];  const float* qw2_b = (const float*)d_in[10];
    const float* ko1_w = (const float*)d_in[11]; const float* ko1_b = (const float*)d_in[12];
    const float* ko2_w = (const float*)d_in[13]; const float* ko2_b = (const float*)d_in[14];
    const float* qo1_w = (const float*)d_in[15]; const float* qo1_b = (const float*)d_in[16];
    const float* qo2_w = (const float*)d_in[17]; const float* qo2_b = (const float*)d_in[18];
    const float* av1_w = (const float*)d_in[19]; const float* av1_b = (const float*)d_in[20];
    const float* av2_w = (const float*)d_in[21]; const float* av2_b = (const float*)d_in[22];
    const float* fv1_w = (const float*)d_in[23]; const float* fv1_b = (const float*)d_in[24];
    const float* fv2_w = (const float*)d_in[25]; const float* fv2_b = (const float*)d_in[26];

    float* out       = (float*)d_out;
    float* out_value = out;                 // B*N*N
    float* out_wz    = out + 131072;        // B*N*N
    float* out_wobs  = out + 262144;        // B*N*N

    const int SZ = 262144;                  // B*N*64
    float* ws    = (float*)d_ws;
    float* M_    = ws;                      // 4096
    float* c_    = ws + 4096;               // 64
    float* kb_   = ws + 4160;               // 4096
    unsigned short* MT_ = (unsigned short*)(ws + 8256);   // 4096 shorts = 2048 floats
    float* kz_   = ws + 10304;
    float* qz_   = kz_   + SZ;
    float* kq_   = qz_   + SZ;
    float* baseq = kq_   + SZ;
    float* dq_   = baseq + SZ;
    float* basev = dq_   + SZ;
    float* dv_   = basev + SZ;
    float* pre_  = dv_   + SZ;
    float* vpf_  = pre_  + SZ;              // end ≈ 9.5 MB

    mm64_kernel<<<1, 256, 0, stream>>>(av2_w, av2_b, fv1_w, M_, MT_, c_);

    setup_kernel<<<NB * 8, 256, 0, stream>>>(
        states, policies, actions,
        kw1_w, kw1_b, kw2_w, kw2_b,
        qw1_w, qw1_b, qw2_w, qw2_b,
        ko1_w, ko1_b, ko2_w, ko2_b,
        qo1_w, qo1_b, qo2_w, qo2_b,
        av1_w, av1_b, fv1_w, fv1_b,
        M_, c_,
        kz_, qz_, kq_, kb_, baseq, dq_, basev, dv_, pre_, vpf_);

    main_kernel<<<NB * NN, 256, 0, stream>>>(
        kz_, qz_, kq_, kb_, baseq, dq_, basev, dv_, pre_, vpf_,
        MT_, c_, fv2_w, fv2_b,
        out_value, out_wz, out_wobs);
}

// Round 7
// 58.863 us; speedup vs baseline: 1.8539x; 1.8539x over previous
//
#include <hip/hip_runtime.h>

#define NB   128
#define NN   32
#define OBS  64
#define ACTD 16
#define HID  64

typedef __attribute__((ext_vector_type(8))) short bf16x8;
typedef __attribute__((ext_vector_type(4))) float f32x4;

__device__ __forceinline__ float leaky(float v) { return v >= 0.f ? v : 0.01f * v; }
__device__ __forceinline__ float wsum64(float p) {
#pragma unroll
    for (int off = 32; off; off >>= 1) p += __shfl_xor(p, off);
    return p;
}
__device__ __forceinline__ unsigned short f2bf(float f) {
    union { float f; unsigned u; } v; v.f = f;
    unsigned r = (v.u + 0x7FFFu + ((v.u >> 16) & 1)) >> 16;
    return (unsigned short)r;
}
__device__ __forceinline__ bf16x8 pack8(const float* v) {
    bf16x8 r;
#pragma unroll
    for (int e = 0; e < 8; ++e) r[e] = (short)f2bf(v[e]);
    return r;
}
// swizzled short-offset for a [*][64] bf16 tile
__device__ __forceinline__ int swz(int row, int col) {
    return row * 64 + ((((col >> 3) ^ (row & 7)) << 3) | (col & 7));
}

// one row per wave: O[h] = (ACT?leaky:id)(bias[h] + sum_k X[k]*W[k*64+h])
template<int K, bool ACT>
__device__ __forceinline__ void layer1(const float* Xrow, const float* __restrict__ W,
                                       const float* __restrict__ bias,
                                       float* Orow, float* __restrict__ Og, int h)
{
    float a0 = bias ? bias[h] : 0.f;
    float a1 = 0.f;
#pragma unroll 8
    for (int k = 0; k < K; k += 2) {
        a0 = fmaf(Xrow[k],     W[k * 64 + h],       a0);
        a1 = fmaf(Xrow[k + 1], W[(k + 1) * 64 + h], a1);
    }
    float v = a0 + a1;
    if (ACT) v = leaky(v);
    if (Orow) Orow[h] = v;
    if (Og)   Og[h]   = v;
}

// ---------------- kernel 0: M = av2_w @ fv1b (f32 + swizzled bf16 M^T), c = av2_b @ fv1b ----------------
__global__ __launch_bounds__(256)
void mm64_kernel(const float* __restrict__ av2_w, const float* __restrict__ av2_b,
                 const float* __restrict__ fv1_w,   // 128x64; rows 64..127 = fv1b
                 float* __restrict__ M, unsigned short* __restrict__ MT,
                 float* __restrict__ c)
{
    const int t = threadIdx.x, h = t & 63, jg = t >> 6;
    __shared__ float sA[64 * 64];
    for (int i = t; i < 4096; i += 256) sA[i] = av2_w[i];
    __syncthreads();
    const float* W = fv1_w + 64 * 64;
    float acc[16];
#pragma unroll
    for (int i = 0; i < 16; ++i) acc[i] = 0.f;
    for (int m = 0; m < 64; ++m) {
        const float w = W[m * 64 + h];
#pragma unroll
        for (int i = 0; i < 16; ++i)
            acc[i] = fmaf(sA[(jg + 4 * i) * 64 + m], w, acc[i]);
    }
#pragma unroll
    for (int i = 0; i < 16; ++i) {
        const int k = jg + 4 * i;
        M[k * 64 + h] = acc[i];
        MT[swz(h, k)] = f2bf(acc[i]);   // MT[h][k] = M[k][h], bf16, swizzled
    }
    if (t < 64) {
        float s = 0.f;
        for (int m = 0; m < 64; ++m) s = fmaf(av2_b[m], W[m * 64 + t], s);
        c[t] = s;
    }
}

// ---------------- kernel 1: row-parallel setup (4 rows/block, 1 row/wave) ----------------
__global__ __launch_bounds__(256)
void setup_kernel(const float* __restrict__ states,    // R,64  (R = B*N = 4096)
                  const float* __restrict__ policies,  // R,16
                  const float* __restrict__ actions,   // R,16
                  const float* __restrict__ kw1_w, const float* __restrict__ kw1_b,
                  const float* __restrict__ kw2_w, const float* __restrict__ kw2_b,
                  const float* __restrict__ qw1_w, const float* __restrict__ qw1_b,
                  const float* __restrict__ qw2_w, const float* __restrict__ qw2_b,
                  const float* __restrict__ ko1_w, const float* __restrict__ ko1_b,
                  const float* __restrict__ ko2_w, const float* __restrict__ ko2_b,
                  const float* __restrict__ qo1_w, const float* __restrict__ qo1_b,
                  const float* __restrict__ qo2_w, const float* __restrict__ qo2_b,
                  const float* __restrict__ av1_w, const float* __restrict__ av1_b,
                  const float* __restrict__ fv1_w, const float* __restrict__ fv1_b,
                  const float* __restrict__ M, const float* __restrict__ c,
                  float* __restrict__ kz,    float* __restrict__ qz,
                  float* __restrict__ kq,    float* __restrict__ kb,
                  float* __restrict__ baseq, float* __restrict__ deltaq,
                  float* __restrict__ basev, float* __restrict__ deltav,
                  float* __restrict__ pre,   float* __restrict__ vpf)
{
    const int r0 = blockIdx.x * 4;        // 1024 blocks × 4 rows
    const int t = threadIdx.x, h = t & 63, jg = t >> 6;
    const int r = r0 + jg;                // this wave's row

    __shared__ float sST[4 * 64];
    __shared__ float sACT[4 * 16], sPOL[4 * 16], sDAP[4 * 16];
    __shared__ float sH[4 * 64], sKZ[4 * 64], sQZ[4 * 64], sKOBS[4 * 64], sBV[4 * 64];
    __shared__ float sSRC[4 * 80];
    __shared__ float T[4096];             // qo2_w row-major, xor-swizzled cols

    if (t < 256) sST[t] = states[r0 * 64 + t];
    if (t < 64) {
        const float av = actions [r0 * 16 + t];
        const float pv = policies[r0 * 16 + t];
        sACT[t] = av; sPOL[t] = pv; sDAP[t] = av - pv;
    }
    for (int i = t; i < 4096; i += 256) {
        const int hh = i >> 6, d = i & 63;
        T[hh * 64 + (d ^ (hh & 31))] = qo2_w[i];
    }
    __syncthreads();   // the only block-wide barrier

    float* ST = sST + jg * 64;
    float* Hr = sH + jg * 64;

    // kz, qz
    layer1<64, true >(ST, kw1_w, kw1_b, Hr, nullptr, h);
    layer1<64, false>(Hr, kw2_w, kw2_b, sKZ + jg * 64, kz + r * 64, h);
    layer1<64, true >(ST, qw1_w, qw1_b, Hr, nullptr, h);
    layer1<64, false>(Hr, qw2_w, qw2_b, sQZ + jg * 64, qz + r * 64, h);

    // wzd = sigmoid(kz.qz/8)
    const float wzd = 1.f / (1.f + __expf(-wsum64(sKZ[jg * 64 + h] * sQZ[jg * 64 + h]) * 0.125f));

    // source row [st, wzd*act + (1-wzd)*pol]
    sSRC[jg * 80 + h] = ST[h];
    if (h < 16)
        sSRC[jg * 80 + 64 + h] = wzd * sACT[jg * 16 + h] + (1.f - wzd) * sPOL[jg * 16 + h];

    // kobs
    layer1<80, true >(sSRC + jg * 80, ko1_w, ko1_b, Hr, nullptr, h);
    layer1<64, false>(Hr, ko2_w, ko2_b, sKOBS + jg * 64, nullptr, h);

    // kq[h] = 0.125*sum_d qo2_w[h][d]*kobs[d]; kb = 0.125*qo2_b.kobs
    {
        float k0 = 0.f;
#pragma unroll 4
        for (int d = 0; d < 64; ++d)
            k0 = fmaf(sKOBS[jg * 64 + d], T[h * 64 + (d ^ (h & 31))], k0);
        kq[r * 64 + h] = k0 * 0.125f;
        const float s0 = wsum64(qo2_b[h] * sKOBS[jg * 64 + h]);
        if (h == 0) kb[r] = s0 * 0.125f;
    }

    // SP row [st, pol]
    if (h < 16) sSRC[jg * 80 + 64 + h] = sPOL[jg * 16 + h];

    layer1<80, false>(sSRC + jg * 80, qo1_w,        qo1_b,   nullptr, baseq  + r * 64, h);
    layer1<16, false>(sDAP + jg * 16, qo1_w + 4096, nullptr, nullptr, deltaq + r * 64, h);
    layer1<80, false>(sSRC + jg * 80, av1_w,        av1_b,   sBV + jg * 64, basev + r * 64, h);
    layer1<16, false>(sDAP + jg * 16, av1_w + 4096, nullptr, nullptr, deltav + r * 64, h);

    // vpf = leaky(basev)@M + c ; pre = st@fv1a + fb1
    Hr[h] = leaky(sBV[jg * 64 + h]);
    layer1<64, false>(Hr, M,     c,     nullptr, vpf + r * 64, h);
    layer1<64, false>(ST, fv1_w, fv1_b, nullptr, pre + r * 64, h);
}

// ---------------- kernel 1b: weight_z per b via MFMA ----------------
__global__ __launch_bounds__(256)
void wz_kernel(const float* __restrict__ kz, const float* __restrict__ qz,
               float* __restrict__ out_wz)   // B,N,N
{
    const int b = blockIdx.x;
    const int t = threadIdx.x, lane = t & 63, jg = t >> 6;
    __shared__ __align__(16) short sKZ[2048], sQZ[2048];

    {
        const int row = t >> 3;
        const int g2 = (t & 7) ^ (row & 7);
        const int base = b * 2048 + t * 8;
        float va[8], vb[8];
        const float4 a0 = *(const float4*)&kz[base], a1 = *(const float4*)&kz[base + 4];
        va[0]=a0.x; va[1]=a0.y; va[2]=a0.z; va[3]=a0.w; va[4]=a1.x; va[5]=a1.y; va[6]=a1.z; va[7]=a1.w;
        const float4 b0 = *(const float4*)&qz[base], b1 = *(const float4*)&qz[base + 4];
        vb[0]=b0.x; vb[1]=b0.y; vb[2]=b0.z; vb[3]=b0.w; vb[4]=b1.x; vb[5]=b1.y; vb[6]=b1.z; vb[7]=b1.w;
        *(bf16x8*)&sKZ[row * 64 + (g2 << 3)] = pack8(va);
        *(bf16x8*)&sQZ[row * 64 + (g2 << 3)] = pack8(vb);
    }
    __syncthreads();

    const int lm = lane & 15, kb8 = lane >> 4;
    const int rt = jg >> 1, ct = jg & 1;   // wave -> (row-tile, col-tile)
    f32x4 acc = {0.f, 0.f, 0.f, 0.f};
#pragma unroll
    for (int k0 = 0; k0 < 64; k0 += 32) {
        const int g = (k0 >> 3) + kb8;
        const int ra = rt * 16 + lm, rb = ct * 16 + lm;
        const bf16x8 af = *(const bf16x8*)&sKZ[ra * 64 + (((g ^ (ra & 7)) << 3))];
        const bf16x8 bf = *(const bf16x8*)&sQZ[rb * 64 + (((g ^ (rb & 7)) << 3))];
        acc = __builtin_amdgcn_mfma_f32_16x16x32_bf16(af, bf, acc, 0, 0, 0);
    }
#pragma unroll
    for (int rr = 0; rr < 4; ++rr) {
        const int arow = rt * 16 + kb8 * 4 + rr;
        const int jcol = ct * 16 + lm;
        out_wz[b * 1024 + arow * 32 + jcol] = 1.f / (1.f + __expf(-acc[rr] * 0.125f));
    }
}

// ---------------- kernel 2: per-(b,a) main ----------------
__global__ __launch_bounds__(256)
void main_kernel(const float* __restrict__ wz,     // B,N,N (out_wz, from wz_kernel)
                 const float* __restrict__ kq,    const float* __restrict__ kb,
                 const float* __restrict__ baseq, const float* __restrict__ deltaq,
                 const float* __restrict__ basev, const float* __restrict__ deltav,
                 const float* __restrict__ pre,   const float* __restrict__ vpf,
                 const unsigned short* __restrict__ MT,  // bf16 swizzled M^T [64][64]
                 const float* __restrict__ c,
                 const float* __restrict__ fv2_w, const float* __restrict__ fv2_b,
                 float* __restrict__ out_value,   // B,N,N
                 float* __restrict__ out_wobs)    // B,N,N
{
    const int bid0 = blockIdx.x;
    const int bid  = (bid0 & 7) * 512 + (bid0 >> 3);   // XCD swizzle (4096 = 8*512)
    const int b = bid >> 5, a = bid & 31;
    const int t = threadIdx.x, lane = t & 63, jg = t >> 6;

    __shared__ __align__(16) short sHQ[2048];   // leaky(bq + wz*dq) bf16 swizzled [32][64]
    __shared__ __align__(16) short sHV[2048];   // leaky(bv + wz*dv)
    __shared__ __align__(16) short sG[2048];    // leaky(g)
    __shared__ __align__(16) short sKQ16[64], sFV2[64];
    __shared__ float sC[32 * 65];               // C = HV@M, padded
    __shared__ float sHBP[4 * 72];              // hbar partials per wave
    __shared__ float sHB[64], sCc[64];
    __shared__ float s_sc[NN], s_w[NN];

    // ---- phase 0: tiny stages + HQ/HV build (coalesced, no barrier needed before) ----
    if (t < 64) {
        sKQ16[t] = (short)f2bf(kq[(b * 32 + a) * 64 + t]);
        sFV2[t]  = (short)f2bf(fv2_w[t]);
        sCc[t]   = c[t];
    }
    const float kbv = kb[b * 32 + a];
    const int   row = t >> 3;                   // this thread's j row (8 elems each)
    const int   g2  = (t & 7) ^ (row & 7);
    const float wzv = wz[b * 1024 + a * 32 + row];
    {
        const int base = b * 2048 + t * 8;
        const float4 q0 = *(const float4*)&baseq[base],  q1 = *(const float4*)&baseq[base + 4];
        const float4 d0 = *(const float4*)&deltaq[base], d1 = *(const float4*)&deltaq[base + 4];
        const float4 v0 = *(const float4*)&basev[base],  v1 = *(const float4*)&basev[base + 4];
        const float4 e0 = *(const float4*)&deltav[base], e1 = *(const float4*)&deltav[base + 4];
        float hq[8], hv[8];
        hq[0]=leaky(q0.x+wzv*d0.x); hq[1]=leaky(q0.y+wzv*d0.y); hq[2]=leaky(q0.z+wzv*d0.z); hq[3]=leaky(q0.w+wzv*d0.w);
        hq[4]=leaky(q1.x+wzv*d1.x); hq[5]=leaky(q1.y+wzv*d1.y); hq[6]=leaky(q1.z+wzv*d1.z); hq[7]=leaky(q1.w+wzv*d1.w);
        hv[0]=leaky(v0.x+wzv*e0.x); hv[1]=leaky(v0.y+wzv*e0.y); hv[2]=leaky(v0.z+wzv*e0.z); hv[3]=leaky(v0.w+wzv*e0.w);
        hv[4]=leaky(v1.x+wzv*e1.x); hv[5]=leaky(v1.y+wzv*e1.y); hv[6]=leaky(v1.z+wzv*e1.z); hv[7]=leaky(v1.w+wzv*e1.w);
        *(bf16x8*)&sHQ[row * 64 + (g2 << 3)] = pack8(hq);
        *(bf16x8*)&sHV[row * 64 + (g2 << 3)] = pack8(hv);
    }
    __syncthreads();

    // ---- phase 1: MFMA — C = HV@M (wave jg -> col-tile jg); waves 0,1 also scores = HQ@kq ----
    {
        const int lm = lane & 15, kb8 = lane >> 4;
        const int bcol = jg * 16 + lm;
        f32x4 acc0 = {0.f,0.f,0.f,0.f}, acc1 = {0.f,0.f,0.f,0.f}, accS = {0.f,0.f,0.f,0.f};
#pragma unroll
        for (int k0 = 0; k0 < 64; k0 += 32) {
            const int g = (k0 >> 3) + kb8;
            const bf16x8 bf = *(const bf16x8*)&MT[bcol * 64 + (((g ^ (bcol & 7)) << 3))];
            const int r0 = lm, r1 = 16 + lm;
            const bf16x8 a0 = *(const bf16x8*)&sHV[r0 * 64 + (((g ^ (r0 & 7)) << 3))];
            const bf16x8 a1 = *(const bf16x8*)&sHV[r1 * 64 + (((g ^ (r1 & 7)) << 3))];
            acc0 = __builtin_amdgcn_mfma_f32_16x16x32_bf16(a0, bf, acc0, 0, 0, 0);
            acc1 = __builtin_amdgcn_mfma_f32_16x16x32_bf16(a1, bf, acc1, 0, 0, 0);
            if (jg < 2) {
                const int rs = jg * 16 + lm;
                const bf16x8 aS = *(const bf16x8*)&sHQ[rs * 64 + (((g ^ (rs & 7)) << 3))];
                bf16x8 bS = {};
                if (lm == 0) bS = *(const bf16x8*)&sKQ16[k0 + kb8 * 8];
                accS = __builtin_amdgcn_mfma_f32_16x16x32_bf16(aS, bS, accS, 0, 0, 0);
            }
        }
#pragma unroll
        for (int rr = 0; rr < 4; ++rr) {
            sC[(kb8 * 4 + rr) * 65 + bcol]      = acc0[rr];
            sC[(16 + kb8 * 4 + rr) * 65 + bcol] = acc1[rr];
        }
        if (jg < 2 && lm == 0) {
#pragma unroll
            for (int rr = 0; rr < 4; ++rr)
                s_sc[jg * 16 + kb8 * 4 + rr] = accS[rr] + kbv;
        }
    }
    __syncthreads();

    // ---- phase 2: in-register softmax (all waves redundant) + hbar partials ----
    float wreg;
    {
        const float sreg = s_sc[lane & 31];
        float m = sreg;
#pragma unroll
        for (int o = 1; o < 32; o <<= 1) m = fmaxf(m, __shfl_xor(m, o));
        const float e = __expf(sreg - m);
        float ssum = e;
#pragma unroll
        for (int o = 1; o < 32; o <<= 1) ssum += __shfl_xor(ssum, o);
        wreg = e / ssum;
        if (t < 32) { s_w[t] = wreg; out_wobs[b * 1024 + a * 32 + t] = wreg; }
        float p = 0.f;
#pragma unroll
        for (int jj = 0; jj < 8; ++jj) {
            const int j = jg * 8 + jj;
            p = fmaf(__shfl(wreg, j), sC[j * 65 + lane], p);
        }
        sHBP[jg * 72 + lane] = p;
    }
    __syncthreads();

    // ---- phase 3: combine hbar ----
    if (t < 64) sHB[t] = (sHBP[t] + sHBP[72 + t]) + (sHBP[144 + t] + sHBP[216 + t]);
    __syncthreads();

    // ---- phase 4: G build (coalesced) ----
    {
        const int base = b * 2048 + t * 8;
        const float4 p0 = *(const float4*)&pre[base], p1 = *(const float4*)&pre[base + 4];
        const float4 f0 = *(const float4*)&vpf[base], f1 = *(const float4*)&vpf[base + 4];
        const float wrow = s_w[row];
        float preL[8] = {p0.x,p0.y,p0.z,p0.w,p1.x,p1.y,p1.z,p1.w};
        float vpfL[8] = {f0.x,f0.y,f0.z,f0.w,f1.x,f1.y,f1.z,f1.w};
        float gv[8];
#pragma unroll
        for (int e = 0; e < 8; ++e) {
            const int col = (t & 7) * 8 + e;
            const float g = preL[e] + (sHB[col] - wrow * sC[row * 65 + col]
                                       + (1.f - wrow) * sCc[col] + wrow * vpfL[e]) * (1.f / 32.f);
            gv[e] = leaky(g);
        }
        *(bf16x8*)&sG[row * 64 + (g2 << 3)] = pack8(gv);
    }
    __syncthreads();

    // ---- phase 5: value = G @ fv2 via MFMA (waves 0,1) ----
    if (jg < 2) {
        const int lm = lane & 15, kb8 = lane >> 4;
        f32x4 accV = {0.f, 0.f, 0.f, 0.f};
#pragma unroll
        for (int k0 = 0; k0 < 64; k0 += 32) {
            const int g = (k0 >> 3) + kb8;
            const int rs = jg * 16 + lm;
            const bf16x8 aG = *(const bf16x8*)&sG[rs * 64 + (((g ^ (rs & 7)) << 3))];
            bf16x8 bF = {};
            if (lm == 0) bF = *(const bf16x8*)&sFV2[k0 + kb8 * 8];
            accV = __builtin_amdgcn_mfma_f32_16x16x32_bf16(aG, bF, accV, 0, 0, 0);
        }
        if (lm == 0) {
            const float fb2 = fv2_b[0];
#pragma unroll
            for (int rr = 0; rr < 4; ++rr)
                out_value[b * 1024 + a * 32 + jg * 16 + kb8 * 4 + rr] = accV[rr] + fb2;
        }
    }
}

extern "C" void kernel_launch(void* const* d_in, const int* in_sizes, int n_in,
                              void* d_out, int out_size, void* d_ws, size_t ws_size,
                              hipStream_t stream)
{
    const float* states   = (const float*)d_in[0];
    const float* policies = (const float*)d_in[1];
    const float* actions  = (const float*)d_in[2];
    const float* kw1_w = (const float*)d_in[3];  const float* kw1_b = (const float*)d_in[4];
    const float* kw2_w = (const float*)d_in[5];  const float* kw2_b = (const float*)d_in[6];
    const float* qw1_w = (const float*)d_in[7];  const float* qw1_b = (const float*)d_in[8];
    const float* qw2_w = (const float*)d_in[9];  const float* qw2_b = (const float*)d_in[10];
    const float* ko1_w = (const float*)d_in[11]; const float* ko1_b = (const float*)d_in[12];
    const float* ko2_w = (const float*)d_in[13]; const float* ko2_b = (const float*)d_in[14];
    const float* qo1_w = (const float*)d_in[15]; const float* qo1_b = (const float*)d_in[16];
    const float* qo2_w = (const float*)d_in[17]; const float* qo2_b = (const float*)d_in[18];
    const float* av1_w = (const float*)d_in[19]; const float* av1_b = (const float*)d_in[20];
    const float* av2_w = (const float*)d_in[21]; const float* av2_b = (const float*)d_in[22];
    const float* fv1_w = (const float*)d_in[23]; const float* fv1_b = (const float*)d_in[24];
    const float* fv2_w = (const float*)d_in[25]; const float* fv2_b = (const float*)d_in[26];

    float* out       = (float*)d_out;
    float* out_value = out;                 // B*N*N
    float* out_wz    = out + 131072;        // B*N*N
    float* out_wobs  = out + 262144;        // B*N*N

    const int SZ = 262144;                  // B*N*64
    float* ws    = (float*)d_ws;
    float* M_    = ws;                      // 4096
    float* c_    = ws + 4096;               // 64
    float* kb_   = ws + 4160;               // 4096
    unsigned short* MT_ = (unsigned short*)(ws + 8256);   // 4096 shorts = 2048 floats
    float* kz_   = ws + 10304;
    float* qz_   = kz_   + SZ;
    float* kq_   = qz_   + SZ;
    float* baseq = kq_   + SZ;
    float* dq_   = baseq + SZ;
    float* basev = dq_   + SZ;
    float* dv_   = basev + SZ;
    float* pre_  = dv_   + SZ;
    float* vpf_  = pre_  + SZ;              // end ≈ 9.5 MB

    mm64_kernel<<<1, 256, 0, stream>>>(av2_w, av2_b, fv1_w, M_, MT_, c_);

    setup_kernel<<<NB * 8, 256, 0, stream>>>(
        states, policies, actions,
        kw1_w, kw1_b, kw2_w, kw2_b,
        qw1_w, qw1_b, qw2_w, qw2_b,
        ko1_w, ko1_b, ko2_w, ko2_b,
        qo1_w, qo1_b, qo2_w, qo2_b,
        av1_w, av1_b, fv1_w, fv1_b,
        M_, c_,
        kz_, qz_, kq_, kb_, baseq, dq_, basev, dv_, pre_, vpf_);

    wz_kernel<<<NB, 256, 0, stream>>>(kz_, qz_, out_wz);

    main_kernel<<<NB * NN, 256, 0, stream>>>(
        out_wz, kq_, kb_, baseq, dq_, basev, dv_, pre_, vpf_,
        MT_, c_, fv2_w, fv2_b,
        out_value, out_wobs);
}

// Round 9
// 40.229 us; speedup vs baseline: 2.7126x; 1.4632x over previous
//
#include <hip/hip_runtime.h>

#define NN   32
#define HID  64

typedef __attribute__((ext_vector_type(8))) short bf16x8;
typedef __attribute__((ext_vector_type(4))) float f32x4;
typedef unsigned short u16;
typedef unsigned int   u32;

__device__ __forceinline__ float leaky(float v) { return v >= 0.f ? v : 0.01f * v; }
__device__ __forceinline__ float wsum64(float p) {
#pragma unroll
    for (int o = 32; o; o >>= 1) p += __shfl_xor(p, o);
    return p;
}
__device__ __forceinline__ u16 f2bf(float f) {
    union { float f; u32 u; } v; v.f = f;
    return (u16)((v.u + 0x7FFFu + ((v.u >> 16) & 1)) >> 16);
}
__device__ __forceinline__ bf16x8 pack8(const float* v) {
    bf16x8 r;
#pragma unroll
    for (int e = 0; e < 8; ++e) r[e] = (short)f2bf(v[e]);
    return r;
}
// swizzled offsets: [row][64] and [row][32] bf16 tiles
__device__ __forceinline__ int swz(int row, int col)   { return row * 64 + ((((col >> 3) ^ (row & 7)) << 3) | (col & 7)); }
__device__ __forceinline__ int swz32(int row, int col) { return row * 32 + ((((col >> 3) ^ (row & 3)) << 3) | (col & 7)); }

// C += A(16xK=64) @ W(cols): A,W both swizzled bf16 tiles (LDS or global)
__device__ __forceinline__ f32x4 gemm64(f32x4 C, const u16* A, const u16* W, int lm, int kb8, int bcol) {
#pragma unroll
    for (int k0 = 0; k0 < 64; k0 += 32) {
        const int g = (k0 >> 3) + kb8;
        const bf16x8 a = *(const bf16x8*)&A[lm * 64 + ((g ^ (lm & 7)) << 3)];
        const bf16x8 w = *(const bf16x8*)&W[bcol * 64 + ((g ^ (bcol & 7)) << 3)];
        C = __builtin_amdgcn_mfma_f32_16x16x32_bf16(a, w, C, 0, 0, 0);
    }
    return C;
}
// C += A(16xK=32) @ W  (K=32 part tiles, zero-padded)
__device__ __forceinline__ f32x4 gemm32(f32x4 C, const u16* A, const u16* W, int lm, int kb8, int bcol) {
    const bf16x8 a = *(const bf16x8*)&A[lm * 32 + ((kb8 ^ (lm & 3)) << 3)];
    const bf16x8 w = *(const bf16x8*)&W[bcol * 32 + ((kb8 ^ (bcol & 3)) << 3)];
    return __builtin_amdgcn_mfma_f32_16x16x32_bf16(a, w, C, 0, 0, 0);
}

// weight-tile offsets (u16 units) inside wt arena
#define W_KW1  0
#define W_KW2  4096
#define W_QW1  8192
#define W_QW2  12288
#define W_KO1A 16384
#define W_KO2  20480
#define W_QO2  24576
#define W_QO1A 28672
#define W_AV1A 32768
#define W_FV1A 36864
#define W_KO1B 40960
#define W_QO1B 43008
#define W_AV1B 45056

// ---------------- kernel 0: weight prep (bf16 swizzled W^T) + MT/c ----------------
__global__ __launch_bounds__(256)
void prep_kernel(const float* __restrict__ av2_w, const float* __restrict__ av2_b,
                 const float* __restrict__ fv1_w,
                 const float* __restrict__ kw1_w, const float* __restrict__ kw2_w,
                 const float* __restrict__ qw1_w, const float* __restrict__ qw2_w,
                 const float* __restrict__ ko1_w, const float* __restrict__ ko2_w,
                 const float* __restrict__ qo2_w, const float* __restrict__ qo1_w,
                 const float* __restrict__ av1_w,
                 u16* __restrict__ MT, float* __restrict__ c, u16* __restrict__ wt)
{
    const int blk = blockIdx.x, t = threadIdx.x;
    if (blk == 0) {
        // MT[h][k] = (av2_w @ fv1b)[k][h] bf16 swizzled ; c = av2_b @ fv1b
        const int h = t & 63, jg = t >> 6;
        __shared__ float sA[4096];
        for (int i = t; i < 4096; i += 256) sA[i] = av2_w[i];
        __syncthreads();
        const float* W = fv1_w + 4096;
        float acc[16];
#pragma unroll
        for (int i = 0; i < 16; ++i) acc[i] = 0.f;
        for (int m = 0; m < 64; ++m) {
            const float w = W[m * 64 + h];
#pragma unroll
            for (int i = 0; i < 16; ++i)
                acc[i] = fmaf(sA[(jg + 4 * i) * 64 + m], w, acc[i]);
        }
#pragma unroll
        for (int i = 0; i < 16; ++i) { const int k = jg + 4 * i; MT[swz(h, k)] = f2bf(acc[i]); }
        if (t < 64) {
            float s = 0.f;
            for (int m = 0; m < 64; ++m) s = fmaf(av2_b[m], W[m * 64 + t], s);
            c[t] = s;
        }
    } else if (blk <= 9) {
        // standard forward layers: Wtile[h][k] = W[k][h]  (transposed)
        const float* srcs[9] = {kw1_w, kw2_w, qw1_w, qw2_w, ko1_w, ko2_w, qo1_w, av1_w, fv1_w};
        const int    offs[9] = {W_KW1, W_KW2, W_QW1, W_QW2, W_KO1A, W_KO2, W_QO1A, W_AV1A, W_FV1A};
        const float* W = srcs[blk - 1]; u16* dst = wt + offs[blk - 1];
        for (int i = t; i < 4096; i += 256) { const int k = i >> 6, h = i & 63; dst[swz(h, k)] = f2bf(W[i]); }
    } else if (blk == 10) {
        // kq path needs the TRANSPOSED product: Wtile[h][d] = qo2_w[h][d]  (identity orientation)
        u16* dst = wt + W_QO2;
        for (int i = t; i < 4096; i += 256) { const int h = i >> 6, d = i & 63; dst[swz(h, d)] = f2bf(qo2_w[i]); }
    } else if (blk <= 13) {
        const float* srcs[3] = {ko1_w + 4096, qo1_w + 4096, av1_w + 4096};
        const int    offs[3] = {W_KO1B, W_QO1B, W_AV1B};
        const float* W = srcs[blk - 11]; u16* dst = wt + offs[blk - 11];
        for (int i = t; i < 1024; i += 256) {
            const int k = i >> 6, h = i & 63;
            dst[swz32(h, k)]      = f2bf(W[i]);
            dst[swz32(h, 16 + k)] = 0;
        }
    }
}

// ---------------- kernel 1: MFMA setup (256 blocks x 16 rows) ----------------
__global__ __launch_bounds__(256)
void setup_kernel(const float* __restrict__ states, const float* __restrict__ policies,
                  const float* __restrict__ actions,
                  const float* __restrict__ kw1_b, const float* __restrict__ kw2_b,
                  const float* __restrict__ qw1_b, const float* __restrict__ qw2_b,
                  const float* __restrict__ ko1_b, const float* __restrict__ ko2_b,
                  const float* __restrict__ qo1_b, const float* __restrict__ qo2_b,
                  const float* __restrict__ av1_b, const float* __restrict__ fv1_b,
                  const u16* __restrict__ wt, const u16* __restrict__ MT,
                  const float* __restrict__ c_,
                  u32* __restrict__ kzg, u32* __restrict__ qzg,
                  float* __restrict__ kq, float* __restrict__ kb,
                  float* __restrict__ baseq, float* __restrict__ deltaq,
                  float* __restrict__ basev, float* __restrict__ deltav,
                  float* __restrict__ pre, float* __restrict__ vpf)
{
    const int blk = blockIdx.x;         // 256 blocks
    const int row0 = blk * 16;          // 16 global rows each
    const int t = threadIdx.x, lane = t & 63, jg = t >> 6;
    const int lm = lane & 15, kb8 = lane >> 4, cg = jg * 16 + lm;

    __shared__ __align__(16) u16 aST[1024], aH1[1024], aH2[1024], aKZ[1024], aQZ[1024];
    __shared__ __align__(16) u16 aP2[512], aDAP[512];
    __shared__ float fACT[256], fPOL[256];
    __shared__ float fKOBS[16 * 68];
    __shared__ float wzd[16];

    // ---- P0: stage inputs ----
    {
        const int i = t * 4, row = i >> 6, col = i & 63;
        const float4 s4 = *(const float4*)&states[row0 * 64 + i];
        const int base = swz(row, col);
        aST[base + 0] = f2bf(s4.x); aST[base + 1] = f2bf(s4.y);
        aST[base + 2] = f2bf(s4.z); aST[base + 3] = f2bf(s4.w);
        const float av = actions[row0 * 16 + t], pv = policies[row0 * 16 + t];
        fACT[t] = av; fPOL[t] = pv;
        const int r2 = t >> 4, cc = t & 15;
        aDAP[swz32(r2, cc)]      = f2bf(av - pv);
        aDAP[swz32(r2, 16 + cc)] = 0;
        aP2 [swz32(r2, 16 + cc)] = 0;
    }
    __syncthreads();

    // ---- P1: H = leaky(ST@kw1 + b) ----
    {
        f32x4 C = {0.f,0.f,0.f,0.f};
        C = gemm64(C, aST, wt + W_KW1, lm, kb8, cg);
        const float bv = kw1_b[cg];
#pragma unroll
        for (int rr = 0; rr < 4; ++rr) aH1[swz(kb8 * 4 + rr, cg)] = f2bf(leaky(C[rr] + bv));
    }
    __syncthreads();

    // ---- P2: KZ = H@kw2 + b ; H2 = leaky(ST@qw1 + b) ----
    {
        f32x4 C = {0.f,0.f,0.f,0.f};
        C = gemm64(C, aH1, wt + W_KW2, lm, kb8, cg);
        const float bv = kw2_b[cg];
#pragma unroll
        for (int rr = 0; rr < 4; ++rr) aKZ[swz(kb8 * 4 + rr, cg)] = f2bf(C[rr] + bv);
        f32x4 D = {0.f,0.f,0.f,0.f};
        D = gemm64(D, aST, wt + W_QW1, lm, kb8, cg);
        const float bq = qw1_b[cg];
#pragma unroll
        for (int rr = 0; rr < 4; ++rr) aH2[swz(kb8 * 4 + rr, cg)] = f2bf(leaky(D[rr] + bq));
    }
    __syncthreads();

    // ---- P3: QZ = H2@qw2 + b ----
    {
        f32x4 C = {0.f,0.f,0.f,0.f};
        C = gemm64(C, aH2, wt + W_QW2, lm, kb8, cg);
        const float bv = qw2_b[cg];
#pragma unroll
        for (int rr = 0; rr < 4; ++rr) aQZ[swz(kb8 * 4 + rr, cg)] = f2bf(C[rr] + bv);
    }
    __syncthreads();

    // ---- P4: wave0 diag(KZ@QZ^T) -> wzd ; waves 1,2 copy KZ/QZ -> global (swizzled bf16) ----
    if (jg == 0) {
        f32x4 C = {0.f,0.f,0.f,0.f};
#pragma unroll
        for (int k0 = 0; k0 < 64; k0 += 32) {
            const int g = (k0 >> 3) + kb8;
            const bf16x8 a  = *(const bf16x8*)&aKZ[lm * 64 + ((g ^ (lm & 7)) << 3)];
            const bf16x8 qb = *(const bf16x8*)&aQZ[lm * 64 + ((g ^ (lm & 7)) << 3)];
            C = __builtin_amdgcn_mfma_f32_16x16x32_bf16(a, qb, C, 0, 0, 0);
        }
        if ((lm >> 2) == kb8) wzd[lm] = 1.f / (1.f + __expf(-C[lm & 3] * 0.125f));
    } else if (jg == 1) {
        const u32* s = (const u32*)aKZ;
        for (int i = lane; i < 512; i += 64) kzg[blk * 512 + i] = s[i];
    } else if (jg == 2) {
        const u32* s = (const u32*)aQZ;
        for (int i = lane; i < 512; i += 64) qzg[blk * 512 + i] = s[i];
    }
    __syncthreads();

    // ---- P5: aP2 = z-part = wzd*act + (1-wzd)*pol ----
    {
        const int r2 = t >> 4, cc = t & 15;
        const float w = wzd[r2];
        aP2[swz32(r2, cc)] = f2bf(w * fACT[t] + (1.f - w) * fPOL[t]);
    }
    __syncthreads();

    // ---- P6: H = leaky(ST@ko1a + P2@ko1b + b) ----
    {
        f32x4 C = {0.f,0.f,0.f,0.f};
        C = gemm64(C, aST, wt + W_KO1A, lm, kb8, cg);
        C = gemm32(C, aP2, wt + W_KO1B, lm, kb8, cg);
        const float bv = ko1_b[cg];
#pragma unroll
        for (int rr = 0; rr < 4; ++rr) aH1[swz(kb8 * 4 + rr, cg)] = f2bf(leaky(C[rr] + bv));
    }
    __syncthreads();

    // ---- P7: KOBS = H@ko2 + b (bf16 + f32) ; aP2 <- pol-part ----
    {
        f32x4 C = {0.f,0.f,0.f,0.f};
        C = gemm64(C, aH1, wt + W_KO2, lm, kb8, cg);
        const float bv = ko2_b[cg];
#pragma unroll
        for (int rr = 0; rr < 4; ++rr) {
            const float v = C[rr] + bv;
            aH2[swz(kb8 * 4 + rr, cg)] = f2bf(v);
            fKOBS[(kb8 * 4 + rr) * 68 + cg] = v;
        }
        const int r2 = t >> 4, cc = t & 15;
        aP2[swz32(r2, cc)] = f2bf(fPOL[t]);
    }
    __syncthreads();

    // ---- P8: kq, kb, baseq, deltaq, basev(+repack), deltav, pre ----
    {
        f32x4 C = {0.f,0.f,0.f,0.f};
        C = gemm64(C, aH2, wt + W_QO2, lm, kb8, cg);   // kq = KOBS @ qo2_w^T (identity-oriented tile)
#pragma unroll
        for (int rr = 0; rr < 4; ++rr) kq[(row0 + kb8 * 4 + rr) * 64 + cg] = C[rr] * 0.125f;
    }
    {
        const float qb = qo2_b[lane];
#pragma unroll
        for (int q = 0; q < 4; ++q) {
            const int r = jg * 4 + q;
            const float s = wsum64(qb * fKOBS[r * 68 + lane]);
            if (lane == 0) kb[row0 + r] = s * 0.125f;
        }
    }
    {
        f32x4 C = {0.f,0.f,0.f,0.f};
        C = gemm64(C, aST, wt + W_QO1A, lm, kb8, cg);
        C = gemm32(C, aP2, wt + W_QO1B, lm, kb8, cg);
        const float bv = qo1_b[cg];
#pragma unroll
        for (int rr = 0; rr < 4; ++rr) baseq[(row0 + kb8 * 4 + rr) * 64 + cg] = C[rr] + bv;
    }
    {
        f32x4 C = {0.f,0.f,0.f,0.f};
        C = gemm32(C, aDAP, wt + W_QO1B, lm, kb8, cg);
#pragma unroll
        for (int rr = 0; rr < 4; ++rr) deltaq[(row0 + kb8 * 4 + rr) * 64 + cg] = C[rr];
    }
    {
        f32x4 C = {0.f,0.f,0.f,0.f};
        C = gemm64(C, aST, wt + W_AV1A, lm, kb8, cg);
        C = gemm32(C, aP2, wt + W_AV1B, lm, kb8, cg);
        const float bv = av1_b[cg];
#pragma unroll
        for (int rr = 0; rr < 4; ++rr) {
            const float v = C[rr] + bv;
            basev[(row0 + kb8 * 4 + rr) * 64 + cg] = v;
            aH1[swz(kb8 * 4 + rr, cg)] = f2bf(leaky(v));
        }
    }
    {
        f32x4 C = {0.f,0.f,0.f,0.f};
        C = gemm32(C, aDAP, wt + W_AV1B, lm, kb8, cg);
#pragma unroll
        for (int rr = 0; rr < 4; ++rr) deltav[(row0 + kb8 * 4 + rr) * 64 + cg] = C[rr];
    }
    {
        f32x4 C = {0.f,0.f,0.f,0.f};
        C = gemm64(C, aST, wt + W_FV1A, lm, kb8, cg);
        const float bv = fv1_b[cg];
#pragma unroll
        for (int rr = 0; rr < 4; ++rr) pre[(row0 + kb8 * 4 + rr) * 64 + cg] = C[rr] + bv;
    }
    __syncthreads();

    // ---- P9: vpf = leaky(basev)@M + c ----
    {
        f32x4 C = {0.f,0.f,0.f,0.f};
        C = gemm64(C, aH1, MT, lm, kb8, cg);
        const float bv = c_[cg];
#pragma unroll
        for (int rr = 0; rr < 4; ++rr) vpf[(row0 + kb8 * 4 + rr) * 64 + cg] = C[rr] + bv;
    }
}

// ---------------- kernel 2: weight_z per b via MFMA ----------------
__global__ __launch_bounds__(256)
void wz_kernel(const u32* __restrict__ kzg, const u32* __restrict__ qzg,
               float* __restrict__ out_wz)   // B,N,N
{
    const int b = blockIdx.x, t = threadIdx.x, lane = t & 63, jg = t >> 6;
    __shared__ __align__(16) u16 sKZ[2048], sQZ[2048];
    u32* kzu = (u32*)sKZ; u32* qzu = (u32*)sQZ;
    for (int i = t; i < 1024; i += 256) { kzu[i] = kzg[b * 1024 + i]; qzu[i] = qzg[b * 1024 + i]; }
    __syncthreads();

    const int lm = lane & 15, kb8 = lane >> 4;
    const int rt = jg >> 1, ct = jg & 1;
    f32x4 acc = {0.f, 0.f, 0.f, 0.f};
#pragma unroll
    for (int k0 = 0; k0 < 64; k0 += 32) {
        const int g = (k0 >> 3) + kb8;
        const int ra = rt * 16 + lm, rb = ct * 16 + lm;
        const bf16x8 af = *(const bf16x8*)&sKZ[ra * 64 + ((g ^ (ra & 7)) << 3)];
        const bf16x8 bf = *(const bf16x8*)&sQZ[rb * 64 + ((g ^ (rb & 7)) << 3)];
        acc = __builtin_amdgcn_mfma_f32_16x16x32_bf16(af, bf, acc, 0, 0, 0);
    }
#pragma unroll
    for (int rr = 0; rr < 4; ++rr) {
        const int arow = rt * 16 + kb8 * 4 + rr;
        const int jcol = ct * 16 + lm;
        out_wz[b * 1024 + arow * 32 + jcol] = 1.f / (1.f + __expf(-acc[rr] * 0.125f));
    }
}

// ---------------- kernel 3: per-(b,a) main (unchanged) ----------------
__global__ __launch_bounds__(256)
void main_kernel(const float* __restrict__ wz,
                 const float* __restrict__ kq,    const float* __restrict__ kb,
                 const float* __restrict__ baseq, const float* __restrict__ deltaq,
                 const float* __restrict__ basev, const float* __restrict__ deltav,
                 const float* __restrict__ pre,   const float* __restrict__ vpf,
                 const u16* __restrict__ MT,
                 const float* __restrict__ c,
                 const float* __restrict__ fv2_w, const float* __restrict__ fv2_b,
                 float* __restrict__ out_value,
                 float* __restrict__ out_wobs)
{
    const int bid0 = blockIdx.x;
    const int bid  = (bid0 & 7) * 512 + (bid0 >> 3);   // XCD swizzle
    const int b = bid >> 5, a = bid & 31;
    const int t = threadIdx.x, lane = t & 63, jg = t >> 6;

    __shared__ __align__(16) short sHQ[2048];
    __shared__ __align__(16) short sHV[2048];
    __shared__ __align__(16) short sG[2048];
    __shared__ __align__(16) short sKQ16[64], sFV2[64];
    __shared__ float sC[32 * 65];
    __shared__ float sHBP[4 * 72];
    __shared__ float sHB[64], sCc[64];
    __shared__ float s_sc[NN], s_w[NN];

    if (t < 64) {
        sKQ16[t] = (short)f2bf(kq[(b * 32 + a) * 64 + t]);
        sFV2[t]  = (short)f2bf(fv2_w[t]);
        sCc[t]   = c[t];
    }
    const float kbv = kb[b * 32 + a];
    const int   row = t >> 3;
    const int   g2  = (t & 7) ^ (row & 7);
    const float wzv = wz[b * 1024 + a * 32 + row];
    {
        const int base = b * 2048 + t * 8;
        const float4 q0 = *(const float4*)&baseq[base],  q1 = *(const float4*)&baseq[base + 4];
        const float4 d0 = *(const float4*)&deltaq[base], d1 = *(const float4*)&deltaq[base + 4];
        const float4 v0 = *(const float4*)&basev[base],  v1 = *(const float4*)&basev[base + 4];
        const float4 e0 = *(const float4*)&deltav[base], e1 = *(const float4*)&deltav[base + 4];
        float hq[8], hv[8];
        hq[0]=leaky(q0.x+wzv*d0.x); hq[1]=leaky(q0.y+wzv*d0.y); hq[2]=leaky(q0.z+wzv*d0.z); hq[3]=leaky(q0.w+wzv*d0.w);
        hq[4]=leaky(q1.x+wzv*d1.x); hq[5]=leaky(q1.y+wzv*d1.y); hq[6]=leaky(q1.z+wzv*d1.z); hq[7]=leaky(q1.w+wzv*d1.w);
        hv[0]=leaky(v0.x+wzv*e0.x); hv[1]=leaky(v0.y+wzv*e0.y); hv[2]=leaky(v0.z+wzv*e0.z); hv[3]=leaky(v0.w+wzv*e0.w);
        hv[4]=leaky(v1.x+wzv*e1.x); hv[5]=leaky(v1.y+wzv*e1.y); hv[6]=leaky(v1.z+wzv*e1.z); hv[7]=leaky(v1.w+wzv*e1.w);
        *(bf16x8*)&sHQ[row * 64 + (g2 << 3)] = pack8(hq);
        *(bf16x8*)&sHV[row * 64 + (g2 << 3)] = pack8(hv);
    }
    __syncthreads();

    {
        const int lm = lane & 15, kb8 = lane >> 4;
        const int bcol = jg * 16 + lm;
        f32x4 acc0 = {0.f,0.f,0.f,0.f}, acc1 = {0.f,0.f,0.f,0.f}, accS = {0.f,0.f,0.f,0.f};
#pragma unroll
        for (int k0 = 0; k0 < 64; k0 += 32) {
            const int g = (k0 >> 3) + kb8;
            const bf16x8 bf = *(const bf16x8*)&MT[bcol * 64 + (((g ^ (bcol & 7)) << 3))];
            const int r0 = lm, r1 = 16 + lm;
            const bf16x8 a0 = *(const bf16x8*)&sHV[r0 * 64 + (((g ^ (r0 & 7)) << 3))];
            const bf16x8 a1 = *(const bf16x8*)&sHV[r1 * 64 + (((g ^ (r1 & 7)) << 3))];
            acc0 = __builtin_amdgcn_mfma_f32_16x16x32_bf16(a0, bf, acc0, 0, 0, 0);
            acc1 = __builtin_amdgcn_mfma_f32_16x16x32_bf16(a1, bf, acc1, 0, 0, 0);
            if (jg < 2) {
                const int rs = jg * 16 + lm;
                const bf16x8 aS = *(const bf16x8*)&sHQ[rs * 64 + (((g ^ (rs & 7)) << 3))];
                bf16x8 bS = {};
                if (lm == 0) bS = *(const bf16x8*)&sKQ16[k0 + kb8 * 8];
                accS = __builtin_amdgcn_mfma_f32_16x16x32_bf16(aS, bS, accS, 0, 0, 0);
            }
        }
#pragma unroll
        for (int rr = 0; rr < 4; ++rr) {
            sC[(kb8 * 4 + rr) * 65 + bcol]      = acc0[rr];
            sC[(16 + kb8 * 4 + rr) * 65 + bcol] = acc1[rr];
        }
        if (jg < 2 && lm == 0) {
#pragma unroll
            for (int rr = 0; rr < 4; ++rr)
                s_sc[jg * 16 + kb8 * 4 + rr] = accS[rr] + kbv;
        }
    }
    __syncthreads();

    float wreg;
    {
        const float sreg = s_sc[lane & 31];
        float m = sreg;
#pragma unroll
        for (int o = 1; o < 32; o <<= 1) m = fmaxf(m, __shfl_xor(m, o));
        const float e = __expf(sreg - m);
        float ssum = e;
#pragma unroll
        for (int o = 1; o < 32; o <<= 1) ssum += __shfl_xor(ssum, o);
        wreg = e / ssum;
        if (t < 32) { s_w[t] = wreg; out_wobs[b * 1024 + a * 32 + t] = wreg; }
        float p = 0.f;
#pragma unroll
        for (int jj = 0; jj < 8; ++jj) {
            const int j = jg * 8 + jj;
            p = fmaf(__shfl(wreg, j), sC[j * 65 + lane], p);
        }
        sHBP[jg * 72 + lane] = p;
    }
    __syncthreads();

    if (t < 64) sHB[t] = (sHBP[t] + sHBP[72 + t]) + (sHBP[144 + t] + sHBP[216 + t]);
    __syncthreads();

    {
        const int base = b * 2048 + t * 8;
        const float4 p0 = *(const float4*)&pre[base], p1 = *(const float4*)&pre[base + 4];
        const float4 f0 = *(const float4*)&vpf[base], f1 = *(const float4*)&vpf[base + 4];
        const float wrow = s_w[row];
        float preL[8] = {p0.x,p0.y,p0.z,p0.w,p1.x,p1.y,p1.z,p1.w};
        float vpfL[8] = {f0.x,f0.y,f0.z,f0.w,f1.x,f1.y,f1.z,f1.w};
        float gv[8];
#pragma unroll
        for (int e = 0; e < 8; ++e) {
            const int col = (t & 7) * 8 + e;
            const float g = preL[e] + (sHB[col] - wrow * sC[row * 65 + col]
                                       + (1.f - wrow) * sCc[col] + wrow * vpfL[e]) * (1.f / 32.f);
            gv[e] = leaky(g);
        }
        *(bf16x8*)&sG[row * 64 + (g2 << 3)] = pack8(gv);
    }
    __syncthreads();

    if (jg < 2) {
        const int lm = lane & 15, kb8 = lane >> 4;
        f32x4 accV = {0.f, 0.f, 0.f, 0.f};
#pragma unroll
        for (int k0 = 0; k0 < 64; k0 += 32) {
            const int g = (k0 >> 3) + kb8;
            const int rs = jg * 16 + lm;
            const bf16x8 aG = *(const bf16x8*)&sG[rs * 64 + (((g ^ (rs & 7)) << 3))];
            bf16x8 bF = {};
            if (lm == 0) bF = *(const bf16x8*)&sFV2[k0 + kb8 * 8];
            accV = __builtin_amdgcn_mfma_f32_16x16x32_bf16(aG, bF, accV, 0, 0, 0);
        }
        if (lm == 0) {
            const float fb2 = fv2_b[0];
#pragma unroll
            for (int rr = 0; rr < 4; ++rr)
                out_value[b * 1024 + a * 32 + jg * 16 + kb8 * 4 + rr] = accV[rr] + fb2;
        }
    }
}

extern "C" void kernel_launch(void* const* d_in, const int* in_sizes, int n_in,
                              void* d_out, int out_size, void* d_ws, size_t ws_size,
                              hipStream_t stream)
{
    const float* states   = (const float*)d_in[0];
    const float* policies = (const float*)d_in[1];
    const float* actions  = (const float*)d_in[2];
    const float* kw1_w = (const float*)d_in[3];  const float* kw1_b = (const float*)d_in[4];
    const float* kw2_w = (const float*)d_in[5];  const float* kw2_b = (const float*)d_in[6];
    const float* qw1_w = (const float*)d_in[7];  const float* qw1_b = (const float*)d_in[8];
    const float* qw2_w = (const float*)d_in[9];  const float* qw2_b = (const float*)d_in[10];
    const float* ko1_w = (const float*)d_in[11]; const float* ko1_b = (const float*)d_in[12];
    const float* ko2_w = (const float*)d_in[13]; const float* ko2_b = (const float*)d_in[14];
    const float* qo1_w = (const float*)d_in[15]; const float* qo1_b = (const float*)d_in[16];
    const float* qo2_w = (const float*)d_in[17]; const float* qo2_b = (const float*)d_in[18];
    const float* av1_w = (const float*)d_in[19]; const float* av1_b = (const float*)d_in[20];
    const float* av2_w = (const float*)d_in[21]; const float* av2_b = (const float*)d_in[22];
    const float* fv1_w = (const float*)d_in[23]; const float* fv1_b = (const float*)d_in[24];
    const float* fv2_w = (const float*)d_in[25]; const float* fv2_b = (const float*)d_in[26];

    float* out       = (float*)d_out;
    float* out_value = out;
    float* out_wz    = out + 131072;
    float* out_wobs  = out + 262144;

    const int SZ = 262144;                       // B*N*64 f32
    float* ws   = (float*)d_ws;
    float* c_   = ws;                            // 64
    float* kb_  = ws + 64;                       // 4096
    u16*   MT_  = (u16*)(ws + 4160);             // 4096 u16
    u32*   kzg  = (u32*)(ws + 6208);             // 131072 u32 (bf16 swz tiles)
    u32*   qzg  = (u32*)(ws + 137280);           // 131072 u32
    float* kq_   = ws + 268352;
    float* baseq = kq_   + SZ;
    float* dq_   = baseq + SZ;
    float* basev = dq_   + SZ;
    float* dv_   = basev + SZ;
    float* pre_  = dv_   + SZ;
    float* vpf_  = pre_  + SZ;
    u16*   wt_   = (u16*)(ws + 2103360);         // 47104 u16 weight arena (~8.5 MB total)

    prep_kernel<<<14, 256, 0, stream>>>(
        av2_w, av2_b, fv1_w,
        kw1_w, kw2_w, qw1_w, qw2_w, ko1_w, ko2_w, qo2_w, qo1_w, av1_w,
        MT_, c_, wt_);

    setup_kernel<<<256, 256, 0, stream>>>(
        states, policies, actions,
        kw1_b, kw2_b, qw1_b, qw2_b, ko1_b, ko2_b, qo1_b, qo2_b, av1_b, fv1_b,
        wt_, MT_, c_,
        kzg, qzg, kq_, kb_, baseq, dq_, basev, dv_, pre_, vpf_);

    wz_kernel<<<128, 256, 0, stream>>>(kzg, qzg, out_wz);

    main_kernel<<<4096, 256, 0, stream>>>(
        out_wz, kq_, kb_, baseq, dq_, basev, dv_, pre_, vpf_,
        MT_, c_, fv2_w, fv2_b,
        out_value, out_wobs);
}